// Round 1
// baseline (617.949 us; speedup 1.0000x reference)
//
#include <hip/hip_runtime.h>
#include <hip/hip_bf16.h>

#define B_ 16
#define C_ 256
#define N_ 4096
#define HD_ 64

typedef float f4 __attribute__((ext_vector_type(4)));
typedef short s8 __attribute__((ext_vector_type(8)));

__device__ __forceinline__ float bf2f(unsigned short u) {
    unsigned int ui = ((unsigned int)u) << 16;
    return __uint_as_float(ui);
}
__device__ __forceinline__ unsigned short f2bf(float f) {
    unsigned int ui = __float_as_uint(f);
    ui += 0x7fffu + ((ui >> 16) & 1u);
    return (unsigned short)(ui >> 16);
}

// ---------------------------------------------------------------------------
// K1: 4 depthwise convs (k=3,5,7,9) from one LDS tile + bias, write y bf16,
//     block-reduce per-(level,group) sum/sumsq -> atomic stats.
// grid (4 htiles, 256 c, 16 b), block 256
// ---------------------------------------------------------------------------
__global__ __launch_bounds__(256) void k1_conv_stats(
    const float* __restrict__ x,
    const float* __restrict__ cw3, const float* __restrict__ cb3,
    const float* __restrict__ cw5, const float* __restrict__ cb5,
    const float* __restrict__ cw7, const float* __restrict__ cb7,
    const float* __restrict__ cw9, const float* __restrict__ cb9,
    unsigned short* __restrict__ y,   // [4][B][C][N] bf16
    float* __restrict__ stats)        // [4][B][4][2]
{
    __shared__ float tile[24 * 72];
    __shared__ float wl[216];
    __shared__ float red[4][8];
    const int t = threadIdx.x;
    const int h0 = blockIdx.x * 16;
    const int c  = blockIdx.y;
    const int b  = blockIdx.z;

    // stage weights (padded row pitches: k9->12, k7->8, k5->8, k3->4)
    if (t < 108)      { int r = t / 12;        int ci = t % 12;       wl[t] = (ci < 9) ? cw9[c*81 + r*9 + ci] : 0.f; }
    else if (t < 164) { int u = t - 108; int r = u / 8; int ci = u % 8; wl[t] = (ci < 7) ? cw7[c*49 + r*7 + ci] : 0.f; }
    else if (t < 204) { int u = t - 164; int r = u / 8; int ci = u % 8; wl[t] = (ci < 5) ? cw5[c*25 + r*5 + ci] : 0.f; }
    else if (t < 216) { int u = t - 204; int r = u / 4; int ci = u % 4; wl[t] = (ci < 3) ? cw3[c*9  + r*3 + ci] : 0.f; }

    // stage x tile: rows h0-4 .. h0+19 (24), cols -4..67 (72), zero pad
    const float* xc = x + (size_t)(b * C_ + c) * N_;
    for (int i = 0; i < 7; ++i) {
        int flat = i * 256 + t;
        if (flat < 24 * 72) {
            int r = flat / 72, col = flat % 72;
            int h = h0 - 4 + r, w = col - 4;
            float v = 0.f;
            if ((unsigned)h < 64u && (unsigned)w < 64u) v = xc[h * 64 + w];
            tile[r * 72 + col] = v;
        }
    }
    __syncthreads();

    const int w4 = (t & 15) * 4;   // 4 horizontal pixels per thread
    const int hr = t >> 4;         // output row h0+hr
    float a3[4] = {0,0,0,0}, a5[4] = {0,0,0,0}, a7[4] = {0,0,0,0}, a9[4] = {0,0,0,0};

    for (int r9 = 0; r9 < 9; ++r9) {
        const float* xr = &tile[(hr + r9) * 72 + w4];
        float xv[12];
        #pragma unroll
        for (int qj = 0; qj < 3; ++qj) {
            f4 tv = *(const f4*)(xr + qj * 4);
            xv[qj*4+0] = tv[0]; xv[qj*4+1] = tv[1]; xv[qj*4+2] = tv[2]; xv[qj*4+3] = tv[3];
        }
        {
            const float* wr = &wl[r9 * 12];
            #pragma unroll
            for (int dx = 0; dx < 9; ++dx) {
                float wv = wr[dx];
                #pragma unroll
                for (int j = 0; j < 4; ++j) a9[j] = fmaf(wv, xv[j + dx], a9[j]);
            }
        }
        int r7 = r9 - 1;
        if ((unsigned)r7 < 7u) {
            const float* wr = &wl[108 + r7 * 8];
            #pragma unroll
            for (int dx = 0; dx < 7; ++dx) {
                float wv = wr[dx];
                #pragma unroll
                for (int j = 0; j < 4; ++j) a7[j] = fmaf(wv, xv[j + dx + 1], a7[j]);
            }
        }
        int r5 = r9 - 2;
        if ((unsigned)r5 < 5u) {
            const float* wr = &wl[164 + r5 * 8];
            #pragma unroll
            for (int dx = 0; dx < 5; ++dx) {
                float wv = wr[dx];
                #pragma unroll
                for (int j = 0; j < 4; ++j) a5[j] = fmaf(wv, xv[j + dx + 2], a5[j]);
            }
        }
        int r3 = r9 - 3;
        if ((unsigned)r3 < 3u) {
            const float* wr = &wl[204 + r3 * 4];
            #pragma unroll
            for (int dx = 0; dx < 3; ++dx) {
                float wv = wr[dx];
                #pragma unroll
                for (int j = 0; j < 4; ++j) a3[j] = fmaf(wv, xv[j + dx + 3], a3[j]);
            }
        }
    }

    float bb0 = cb3[c], bb1 = cb5[c], bb2 = cb7[c], bb3 = cb9[c];
    float va[4][4];
    #pragma unroll
    for (int j = 0; j < 4; ++j) {
        va[0][j] = a3[j] + bb0; va[1][j] = a5[j] + bb1;
        va[2][j] = a7[j] + bb2; va[3][j] = a9[j] + bb3;
    }

    float s[4], ss[4];
    const size_t L = (size_t)B_ * C_ * N_;
    size_t ybase = (size_t)(b * C_ + c) * N_ + (size_t)(h0 + hr) * 64 + w4;
    #pragma unroll
    for (int l = 0; l < 4; ++l) {
        float s1 = 0.f, s2 = 0.f;
        ushort4 pk;
        pk.x = f2bf(va[l][0]); pk.y = f2bf(va[l][1]);
        pk.z = f2bf(va[l][2]); pk.w = f2bf(va[l][3]);
        #pragma unroll
        for (int j = 0; j < 4; ++j) { s1 += va[l][j]; s2 += va[l][j] * va[l][j]; }
        *reinterpret_cast<ushort4*>(y + (size_t)l * L + ybase) = pk;
        s[l] = s1; ss[l] = s2;
    }

    #pragma unroll
    for (int l = 0; l < 4; ++l) {
        float aa = s[l], qq = ss[l];
        for (int off = 1; off < 64; off <<= 1) { aa += __shfl_xor(aa, off); qq += __shfl_xor(qq, off); }
        s[l] = aa; ss[l] = qq;
    }
    const int lane = t & 63, wvi = t >> 6;
    if (lane == 0) {
        #pragma unroll
        for (int l = 0; l < 4; ++l) { red[wvi][l*2] = s[l]; red[wvi][l*2+1] = ss[l]; }
    }
    __syncthreads();
    if (t < 8) {
        float tot = red[0][t] + red[1][t] + red[2][t] + red[3][t];
        int l = t >> 1, which = t & 1, g = c >> 6;
        atomicAdd(&stats[((l * 16 + b) * 4 + g) * 2 + which], tot);
    }
}

// ---------------------------------------------------------------------------
// K2: groupnorm + sigmoid + softmax-weighted fusion; write fused [b,c,n] fp32
//     and xs [b,n,c] bf16 (via LDS transpose).
// grid (64 ntiles, 4 groups, 16 b), block 256
// ---------------------------------------------------------------------------
__global__ __launch_bounds__(256) void k2_fuse(
    const unsigned short* __restrict__ y, const float* __restrict__ stats,
    const float* __restrict__ gnw, const float* __restrict__ gnb,
    const float* __restrict__ fw,
    unsigned short* __restrict__ xs, float* __restrict__ fused)
{
    __shared__ float tile[64 * 65];
    const int t = threadIdx.x;
    const int n0 = blockIdx.x * 64;
    const int cg = blockIdx.y;
    const int b  = blockIdx.z;
    const int c0 = cg * 64;

    float f0 = fw[0], f1 = fw[1], f2 = fw[2], f3 = fw[3];
    float mx = fmaxf(fmaxf(f0, f1), fmaxf(f2, f3));
    float e0 = __expf(f0 - mx), e1 = __expf(f1 - mx), e2 = __expf(f2 - mx), e3 = __expf(f3 - mx);
    float inv = 1.f / (e0 + e1 + e2 + e3);
    float wts[4] = { e0 * inv, e1 * inv, e2 * inv, e3 * inv };

    float mean[4], rstd[4];
    const float invN = 1.0f / 262144.0f;
    #pragma unroll
    for (int l = 0; l < 4; ++l) {
        float s1 = stats[((l * 16 + b) * 4 + cg) * 2 + 0];
        float s2 = stats[((l * 16 + b) * 4 + cg) * 2 + 1];
        float m = s1 * invN;
        float var = fmaxf(s2 * invN - m * m, 0.f);
        mean[l] = m; rstd[l] = rsqrtf(var + 1e-5f);
    }
    const size_t L = (size_t)B_ * C_ * N_;
    for (int i = 0; i < 16; ++i) {
        int ci = i * 4 + (t >> 6);
        int nj = t & 63;
        int c = c0 + ci;
        size_t base = (size_t)(b * C_ + c) * N_ + n0 + nj;
        float acc = 0.f;
        #pragma unroll
        for (int l = 0; l < 4; ++l) {
            float yv = bf2f(y[(size_t)l * L + base]);
            float g = (yv - mean[l]) * rstd[l] * gnw[l * 256 + c] + gnb[l * 256 + c];
            acc += wts[l] * (1.0f / (1.0f + __expf(-g)));
        }
        fused[base] = acc;
        tile[ci * 65 + nj] = acc;
    }
    __syncthreads();
    for (int i = 0; i < 16; ++i) {
        int nj = i * 4 + (t >> 6);
        int ci = t & 63;
        xs[((size_t)b * N_ + n0 + nj) * C_ + c0 + ci] = f2bf(tile[ci * 65 + nj]);
    }
}

// convert qk_w fp32 -> bf16
__global__ __launch_bounds__(256) void k2b_cvt(const float* __restrict__ w,
                                              unsigned short* __restrict__ o, int n)
{
    int i = blockIdx.x * 256 + threadIdx.x;
    if (i < n) o[i] = f2bf(w[i]);
}

// ---------------------------------------------------------------------------
// K3: qk = xs @ qk_w^T via bf16 MFMA 16x16x32, epilogue elu+1, fp32 out.
// A [65536][256] bf16, B^T [512][256] bf16, C [65536][512] fp32.
// grid (256, 8), block 256 (4 waves, each 64x64 tile)
// ---------------------------------------------------------------------------
__global__ __launch_bounds__(256) void k3_gemm(
    const short* __restrict__ A, const short* __restrict__ Bw,
    float* __restrict__ qk)
{
    const int t = threadIdx.x, lane = t & 63, wv = t >> 6;
    const int m0 = blockIdx.x * 256 + wv * 64;
    const int n0 = blockIdx.y * 64;
    const int mr = lane & 15, koff = (lane >> 4) * 8;

    f4 acc[4][4];
    #pragma unroll
    for (int a = 0; a < 4; ++a)
        #pragma unroll
        for (int bn = 0; bn < 4; ++bn) { acc[a][bn][0]=0.f; acc[a][bn][1]=0.f; acc[a][bn][2]=0.f; acc[a][bn][3]=0.f; }

    for (int k0 = 0; k0 < 256; k0 += 32) {
        s8 af[4], bf[4];
        #pragma unroll
        for (int mt = 0; mt < 4; ++mt)
            af[mt] = *(const s8*)(A + (size_t)(m0 + mt * 16 + mr) * 256 + k0 + koff);
        #pragma unroll
        for (int nt = 0; nt < 4; ++nt)
            bf[nt] = *(const s8*)(Bw + (size_t)(n0 + nt * 16 + mr) * 256 + k0 + koff);
        #pragma unroll
        for (int mt = 0; mt < 4; ++mt)
            #pragma unroll
            for (int nt = 0; nt < 4; ++nt)
                acc[mt][nt] = __builtin_amdgcn_mfma_f32_16x16x32_bf16(af[mt], bf[nt], acc[mt][nt], 0, 0, 0);
    }

    const int rbase = (lane >> 4) * 4;
    #pragma unroll
    for (int mt = 0; mt < 4; ++mt)
        #pragma unroll
        for (int nt = 0; nt < 4; ++nt)
            #pragma unroll
            for (int r = 0; r < 4; ++r) {
                int m = m0 + mt * 16 + rbase + r;
                int n = n0 + nt * 16 + mr;
                float v = acc[mt][nt][r];
                v = v > 0.f ? v + 1.f : __expf(v);   // elu(v)+1
                qk[(size_t)m * 512 + n] = v;
            }
}

// ---------------------------------------------------------------------------
// K4: k_mean over n per (b, c). grid (64 nchunks, 16 b), block 256
// ---------------------------------------------------------------------------
__global__ __launch_bounds__(256) void k4_kmean(const float* __restrict__ qk,
                                                float* __restrict__ kmean)
{
    const int t = threadIdx.x, chunk = blockIdx.x, b = blockIdx.y;
    const float* base = qk + (size_t)b * N_ * 512 + (size_t)chunk * 64 * 512 + 256 + t;
    float s = 0.f;
    for (int j = 0; j < 64; ++j) s += base[(size_t)j * 512];
    atomicAdd(&kmean[b * 256 + t], s * (1.0f / 4096.0f));
}

// ---------------------------------------------------------------------------
// K5: kv[b,h,d,e] = (1/n) sum_n k_rope[n,d] * v[n,e]. split-K over n, atomics.
// grid (16 splits, 4 h, 16 b), block 256
// ---------------------------------------------------------------------------
__global__ __launch_bounds__(256) void k5_kv(
    const float* __restrict__ qk, const unsigned short* __restrict__ xs,
    float* __restrict__ kv)
{
    __shared__ float kl[64 * 68];
    __shared__ float vl[64 * 68];
    const int t = threadIdx.x, lane = t & 63, wv = t >> 6;
    const int split = blockIdx.x, h = blockIdx.y, b = blockIdx.z;
    const int ch = h * 64 + lane;
    const int jj = ch >> 1;
    const float theta = exp2f(-(float)jj * (13.287712379549449f / 128.f)); // 10000^(-jj/128)

    const int d4 = (t & 15) * 4, e4 = (t >> 4) * 4;
    f4 acc4[4];
    #pragma unroll
    for (int i = 0; i < 4; ++i) { acc4[i][0]=0.f; acc4[i][1]=0.f; acc4[i][2]=0.f; acc4[i][3]=0.f; }

    for (int sc = 0; sc < 4; ++sc) {
        const int nbase = split * 256 + sc * 64;
        for (int i = 0; i < 16; ++i) {
            int nl = i * 4 + wv;
            int n = nbase + nl;
            float val = qk[((size_t)b * N_ + n) * 512 + 256 + ch];
            float pv = __shfl_xor(val, 1);
            float ang = (float)(n & 63) * theta;
            float sv, cv; sincosf(ang, &sv, &cv);
            float kr = (lane & 1) ? (sv * pv + cv * val) : (cv * val - sv * pv);
            kl[nl * 68 + lane] = kr;
            vl[nl * 68 + lane] = bf2f(xs[((size_t)b * N_ + n) * 256 + ch]);
        }
        __syncthreads();
        for (int nn = 0; nn < 64; ++nn) {
            f4 kk = *(const f4*)&kl[nn * 68 + d4];
            f4 vv = *(const f4*)&vl[nn * 68 + e4];
            acc4[0] += vv * kk[0];
            acc4[1] += vv * kk[1];
            acc4[2] += vv * kk[2];
            acc4[3] += vv * kk[3];
        }
        __syncthreads();
    }
    const float scale = 1.0f / 4096.0f;
    float* kvp = kv + (size_t)(b * 4 + h) * 4096;
    #pragma unroll
    for (int i = 0; i < 4; ++i)
        #pragma unroll
        for (int j = 0; j < 4; ++j)
            atomicAdd(&kvp[(d4 + i) * 64 + e4 + j], acc4[i][j] * scale);
}

// ---------------------------------------------------------------------------
// K6: attn = (q_rope @ kv) * z, z = 1/(q . kmean + 1e-6); write d_out [b,c,n].
// grid (64 nchunks, 4 h, 16 b), block 256
// ---------------------------------------------------------------------------
__global__ __launch_bounds__(256) void k6_attn(
    const float* __restrict__ qk, const float* __restrict__ kmean,
    const float* __restrict__ kv, float* __restrict__ out)
{
    __shared__ float kvl[64 * 64];
    __shared__ float qT[64 * 68];
    __shared__ float zl[64];
    const int t = threadIdx.x, lane = t & 63, wv = t >> 6;
    const int nt = blockIdx.x, h = blockIdx.y, b = blockIdx.z;
    const int n0 = nt * 64;
    const int ch = h * 64 + lane;
    const int jj = ch >> 1;
    const float theta = exp2f(-(float)jj * (13.287712379549449f / 128.f));
    const float km = kmean[b * 256 + ch];

    for (int i = 0; i < 16; ++i) {
        int flat = i * 256 + t;
        kvl[flat] = kv[(size_t)(b * 4 + h) * 4096 + flat];
    }
    for (int i = 0; i < 16; ++i) {
        int nl = i * 4 + wv;
        int n = n0 + nl;
        float val = qk[((size_t)b * N_ + n) * 512 + ch];
        float pv = __shfl_xor(val, 1);
        float ang = (float)(n & 63) * theta;
        float sv, cv; sincosf(ang, &sv, &cv);
        float qr = (lane & 1) ? (sv * pv + cv * val) : (cv * val - sv * pv);
        qT[lane * 68 + nl] = qr;
        float zd = val * km;
        for (int off = 1; off < 64; off <<= 1) zd += __shfl_xor(zd, off);
        if (lane == 0) zl[nl] = 1.0f / (zd + 1e-6f);
    }
    __syncthreads();

    const int n4 = (t & 15) * 4, e4 = (t >> 4) * 4;
    f4 acc[4];
    #pragma unroll
    for (int j = 0; j < 4; ++j) { acc[j][0]=0.f; acc[j][1]=0.f; acc[j][2]=0.f; acc[j][3]=0.f; }
    for (int dd = 0; dd < 64; ++dd) {
        f4 qq = *(const f4*)&qT[dd * 68 + n4];
        f4 kk = *(const f4*)&kvl[dd * 64 + e4];
        acc[0] += qq * kk[0];
        acc[1] += qq * kk[1];
        acc[2] += qq * kk[2];
        acc[3] += qq * kk[3];
    }
    f4 z4 = *(const f4*)&zl[n4];
    #pragma unroll
    for (int j = 0; j < 4; ++j) acc[j] *= z4;
    #pragma unroll
    for (int j = 0; j < 4; ++j)
        *(f4*)&out[(size_t)(b * 256 + h * 64 + e4 + j) * N_ + n0 + n4] = acc[j];
}

// ---------------------------------------------------------------------------
// K7: LePE 3x3 depthwise conv on fused + bias, RMW-add into d_out.
// grid (256 c, 16 b), block 256
// ---------------------------------------------------------------------------
__global__ __launch_bounds__(256) void k7_lepe(
    const float* __restrict__ fused, const float* __restrict__ lw,
    const float* __restrict__ lb, float* __restrict__ out)
{
    __shared__ float tile[66 * 68];
    const int t = threadIdx.x;
    const int c = blockIdx.x, b = blockIdx.y;
    const float* fc = fused + (size_t)(b * C_ + c) * N_;
    for (int i = 0; i < 18; ++i) {
        int flat = i * 256 + t;
        if (flat < 66 * 68) {
            int r = flat / 68, col = flat % 68;
            int h = r - 1, w = col - 1;
            float v = 0.f;
            if ((unsigned)h < 64u && (unsigned)w < 64u) v = fc[h * 64 + w];
            tile[r * 68 + col] = v;
        }
    }
    __syncthreads();
    float w00 = lw[c*9+0], w01 = lw[c*9+1], w02 = lw[c*9+2];
    float w10 = lw[c*9+3], w11 = lw[c*9+4], w12 = lw[c*9+5];
    float w20 = lw[c*9+6], w21 = lw[c*9+7], w22 = lw[c*9+8];
    float bias = lb[c];
    const int w4 = (t & 15) * 4;
    float* oc = out + (size_t)(b * C_ + c) * N_;
    for (int hh = 0; hh < 4; ++hh) {
        int h = (t >> 4) + hh * 16;
        float r0[6], r1[6], r2[6];
        #pragma unroll
        for (int u = 0; u < 6; ++u) {
            r0[u] = tile[(h + 0) * 68 + w4 + u];
            r1[u] = tile[(h + 1) * 68 + w4 + u];
            r2[u] = tile[(h + 2) * 68 + w4 + u];
        }
        f4 prev = *(const f4*)&oc[h * 64 + w4];
        #pragma unroll
        for (int j = 0; j < 4; ++j) {
            float o = bias;
            o = fmaf(w00, r0[j],   o); o = fmaf(w01, r0[j+1], o); o = fmaf(w02, r0[j+2], o);
            o = fmaf(w10, r1[j],   o); o = fmaf(w11, r1[j+1], o); o = fmaf(w12, r1[j+2], o);
            o = fmaf(w20, r2[j],   o); o = fmaf(w21, r2[j+1], o); o = fmaf(w22, r2[j+2], o);
            prev[j] += o;
        }
        *(f4*)&oc[h * 64 + w4] = prev;
    }
}

// ---------------------------------------------------------------------------
extern "C" void kernel_launch(void* const* d_in, const int* in_sizes, int n_in,
                              void* d_out, int out_size, void* d_ws, size_t ws_size,
                              hipStream_t stream)
{
    const float* x   = (const float*)d_in[0];
    const float* w3  = (const float*)d_in[1];  const float* b3 = (const float*)d_in[2];
    const float* w5  = (const float*)d_in[3];  const float* b5 = (const float*)d_in[4];
    const float* w7  = (const float*)d_in[5];  const float* b7 = (const float*)d_in[6];
    const float* w9  = (const float*)d_in[7];  const float* b9 = (const float*)d_in[8];
    const float* gnw = (const float*)d_in[9];  const float* gnb = (const float*)d_in[10];
    const float* fw  = (const float*)d_in[11];
    const float* qkw = (const float*)d_in[12];
    const float* lw  = (const float*)d_in[13]; const float* lb = (const float*)d_in[14];

    char* ws = (char*)d_ws;
    // layout (bytes):
    //   [0, 128MiB)        y bf16 [4][B][C][N]   -- later ALIASED by qk fp32 [65536][512]
    //   [128MiB, +32MiB)   xs bf16 [B][N][C]
    //   [.. , +64MiB)      fused fp32 [B][C][N]
    //   [.. , +256KiB)     qk_w bf16
    //   [..]               stats (2KB) | kmean (16KB) | kv (4MB)  -- one memset
    unsigned short* y     = (unsigned short*)(ws + 0);
    float*          qk    = (float*)(ws + 0);
    unsigned short* xs    = (unsigned short*)(ws + 134217728ull);
    float*          fused = (float*)(ws + 167772160ull);
    unsigned short* wb    = (unsigned short*)(ws + 234881024ull);
    float*          stats = (float*)(ws + 235143168ull);
    float*          kmean = (float*)(ws + 235145216ull);
    float*          kv    = (float*)(ws + 235161600ull);

    hipMemsetAsync(stats, 0, 2048 + 16384 + 4194304, stream);

    k1_conv_stats<<<dim3(4, 256, 16), 256, 0, stream>>>(x, w3, b3, w5, b5, w7, b7, w9, b9, y, stats);
    k2b_cvt<<<dim3(512), 256, 0, stream>>>(qkw, wb, 131072);
    k2_fuse<<<dim3(64, 4, 16), 256, 0, stream>>>(y, stats, gnw, gnb, fw, xs, fused);
    k3_gemm<<<dim3(256, 8), 256, 0, stream>>>((const short*)xs, (const short*)wb, qk);
    k4_kmean<<<dim3(64, 16), 256, 0, stream>>>(qk, kmean);
    k5_kv<<<dim3(16, 4, 16), 256, 0, stream>>>(qk, xs, kv);
    k6_attn<<<dim3(64, 4, 16), 256, 0, stream>>>(qk, kmean, kv, (float*)d_out);
    k7_lepe<<<dim3(256, 16), 256, 0, stream>>>(fused, lw, lb, (float*)d_out);
}

// Round 3
// 560.711 us; speedup vs baseline: 1.1021x; 1.1021x over previous
//
#include <hip/hip_runtime.h>
#include <hip/hip_bf16.h>

#define B_ 16
#define C_ 256
#define N_ 4096
#define HD_ 64

typedef float f4 __attribute__((ext_vector_type(4)));
typedef short s8 __attribute__((ext_vector_type(8)));
typedef unsigned short us8 __attribute__((ext_vector_type(8)));

__device__ __forceinline__ float bf2f(unsigned short u) {
    unsigned int ui = ((unsigned int)u) << 16;
    return __uint_as_float(ui);
}
__device__ __forceinline__ unsigned short f2bf(float f) {
    unsigned int ui = __float_as_uint(f);
    ui += 0x7fffu + ((ui >> 16) & 1u);
    return (unsigned short)(ui >> 16);
}

// ---------------------------------------------------------------------------
// K1: 4 depthwise convs (k=3,5,7,9) from one LDS x-tile; weights read via
//     block-uniform global loads (scalar path, NOT LDS). 8 px/thread.
//     Write y bf16, block-reduce per-(level,group) sum/sumsq -> atomic stats.
// grid (2 htiles, 256 c, 16 b), block 256. Tile: 40 rows x 76-pitch.
// ---------------------------------------------------------------------------
__global__ __launch_bounds__(256) void k1_conv_stats(
    const float* __restrict__ x,
    const float* __restrict__ cw3, const float* __restrict__ cb3,
    const float* __restrict__ cw5, const float* __restrict__ cb5,
    const float* __restrict__ cw7, const float* __restrict__ cb7,
    const float* __restrict__ cw9, const float* __restrict__ cb9,
    unsigned short* __restrict__ y,   // [4][B][C][N] bf16
    float* __restrict__ stats)        // [4][B][4][2]
{
    __shared__ float tile[40 * 76];   // pitch 76: bank shift 12/row, 16B aligned
    __shared__ float red[4][8];
    const int t = threadIdx.x;
    const int h0 = blockIdx.x * 32;
    const int c  = blockIdx.y;
    const int b  = blockIdx.z;

    // stage x tile: rows h0-4 .. h0+35 (40), cols -4..67 (72 used of 76), zero pad
    const float* xc = x + (size_t)(b * C_ + c) * N_;
    for (int i = 0; i < 12; ++i) {
        int flat = i * 256 + t;
        if (flat < 40 * 76) {
            int r = flat / 76, col = flat % 76;
            int h = h0 - 4 + r, w = col - 4;
            float v = 0.f;
            if ((unsigned)h < 64u && (unsigned)w < 64u && col < 72) v = xc[h * 64 + w];
            tile[flat] = v;
        }
    }
    __syncthreads();

    const int w8 = (t & 7) * 8;   // 8 horizontal pixels per thread
    const int hr = t >> 3;        // output row h0+hr  (0..31)
    float a3[8], a5[8], a7[8], a9[8];
    #pragma unroll
    for (int j = 0; j < 8; ++j) { a3[j]=0.f; a5[j]=0.f; a7[j]=0.f; a9[j]=0.f; }

    const float* w9p = cw9 + c * 81;
    const float* w7p = cw7 + c * 49;
    const float* w5p = cw5 + c * 25;
    const float* w3p = cw3 + c * 9;

    #pragma unroll 1
    for (int r9 = 0; r9 < 9; ++r9) {
        const float* xr = &tile[(hr + r9) * 76 + w8];
        float xv[16];
        #pragma unroll
        for (int q = 0; q < 4; ++q) {
            f4 tv = *(const f4*)(xr + q * 4);
            xv[q*4+0] = tv[0]; xv[q*4+1] = tv[1]; xv[q*4+2] = tv[2]; xv[q*4+3] = tv[3];
        }
        {
            #pragma unroll
            for (int dx = 0; dx < 9; ++dx) {
                float wv = w9p[r9 * 9 + dx];       // block-uniform -> scalar load
                #pragma unroll
                for (int j = 0; j < 8; ++j) a9[j] = fmaf(wv, xv[j + dx], a9[j]);
            }
        }
        int r7 = r9 - 1;
        if ((unsigned)r7 < 7u) {
            #pragma unroll
            for (int dx = 0; dx < 7; ++dx) {
                float wv = w7p[r7 * 7 + dx];
                #pragma unroll
                for (int j = 0; j < 8; ++j) a7[j] = fmaf(wv, xv[j + dx + 1], a7[j]);
            }
        }
        int r5 = r9 - 2;
        if ((unsigned)r5 < 5u) {
            #pragma unroll
            for (int dx = 0; dx < 5; ++dx) {
                float wv = w5p[r5 * 5 + dx];
                #pragma unroll
                for (int j = 0; j < 8; ++j) a5[j] = fmaf(wv, xv[j + dx + 2], a5[j]);
            }
        }
        int r3 = r9 - 3;
        if ((unsigned)r3 < 3u) {
            #pragma unroll
            for (int dx = 0; dx < 3; ++dx) {
                float wv = w3p[r3 * 3 + dx];
                #pragma unroll
                for (int j = 0; j < 8; ++j) a3[j] = fmaf(wv, xv[j + dx + 3], a3[j]);
            }
        }
    }

    float bb0 = cb3[c], bb1 = cb5[c], bb2 = cb7[c], bb3 = cb9[c];
    float s[4], ss[4];
    const size_t L = (size_t)B_ * C_ * N_;
    size_t ybase = (size_t)(b * C_ + c) * N_ + (size_t)(h0 + hr) * 64 + w8;

    #pragma unroll
    for (int l = 0; l < 4; ++l) {
        float bias = (l == 0) ? bb0 : (l == 1) ? bb1 : (l == 2) ? bb2 : bb3;
        float* ap = (l == 0) ? a3 : (l == 1) ? a5 : (l == 2) ? a7 : a9;
        float s1 = 0.f, s2 = 0.f;
        us8 pk;
        #pragma unroll
        for (int j = 0; j < 8; ++j) {
            float v = ap[j] + bias;
            pk[j] = f2bf(v);
            s1 += v; s2 += v * v;
        }
        *reinterpret_cast<us8*>(y + (size_t)l * L + ybase) = pk;
        s[l] = s1; ss[l] = s2;
    }

    #pragma unroll
    for (int l = 0; l < 4; ++l) {
        float aa = s[l], qq = ss[l];
        for (int off = 1; off < 64; off <<= 1) { aa += __shfl_xor(aa, off); qq += __shfl_xor(qq, off); }
        s[l] = aa; ss[l] = qq;
    }
    const int lane = t & 63, wvi = t >> 6;
    if (lane == 0) {
        #pragma unroll
        for (int l = 0; l < 4; ++l) { red[wvi][l*2] = s[l]; red[wvi][l*2+1] = ss[l]; }
    }
    __syncthreads();
    if (t < 8) {
        float tot = red[0][t] + red[1][t] + red[2][t] + red[3][t];
        int l = t >> 1, which = t & 1, g = c >> 6;
        atomicAdd(&stats[((l * 16 + b) * 4 + g) * 2 + which], tot);
    }
}

// ---------------------------------------------------------------------------
// K2: groupnorm + sigmoid + softmax-weighted fusion; write fused [b,c,n] fp32
//     and xs [b,n,c] bf16 (via LDS transpose).
// grid (64 ntiles, 4 groups, 16 b), block 256
// ---------------------------------------------------------------------------
__global__ __launch_bounds__(256) void k2_fuse(
    const unsigned short* __restrict__ y, const float* __restrict__ stats,
    const float* __restrict__ gnw, const float* __restrict__ gnb,
    const float* __restrict__ fw,
    unsigned short* __restrict__ xs, float* __restrict__ fused)
{
    __shared__ float tile[64 * 65];
    const int t = threadIdx.x;
    const int n0 = blockIdx.x * 64;
    const int cg = blockIdx.y;
    const int b  = blockIdx.z;
    const int c0 = cg * 64;

    float f0 = fw[0], f1 = fw[1], f2 = fw[2], f3 = fw[3];
    float mx = fmaxf(fmaxf(f0, f1), fmaxf(f2, f3));
    float e0 = __expf(f0 - mx), e1 = __expf(f1 - mx), e2 = __expf(f2 - mx), e3 = __expf(f3 - mx);
    float inv = 1.f / (e0 + e1 + e2 + e3);
    float wts[4] = { e0 * inv, e1 * inv, e2 * inv, e3 * inv };

    float mean[4], rstd[4];
    const float invN = 1.0f / 262144.0f;
    #pragma unroll
    for (int l = 0; l < 4; ++l) {
        float s1 = stats[((l * 16 + b) * 4 + cg) * 2 + 0];
        float s2 = stats[((l * 16 + b) * 4 + cg) * 2 + 1];
        float m = s1 * invN;
        float var = fmaxf(s2 * invN - m * m, 0.f);
        mean[l] = m; rstd[l] = rsqrtf(var + 1e-5f);
    }
    const size_t L = (size_t)B_ * C_ * N_;
    for (int i = 0; i < 16; ++i) {
        int ci = i * 4 + (t >> 6);
        int nj = t & 63;
        int c = c0 + ci;
        size_t base = (size_t)(b * C_ + c) * N_ + n0 + nj;
        float acc = 0.f;
        #pragma unroll
        for (int l = 0; l < 4; ++l) {
            float yv = bf2f(y[(size_t)l * L + base]);
            float g = (yv - mean[l]) * rstd[l] * gnw[l * 256 + c] + gnb[l * 256 + c];
            acc += wts[l] * (1.0f / (1.0f + __expf(-g)));
        }
        fused[base] = acc;
        tile[ci * 65 + nj] = acc;
    }
    __syncthreads();
    for (int i = 0; i < 16; ++i) {
        int nj = i * 4 + (t >> 6);
        int ci = t & 63;
        xs[((size_t)b * N_ + n0 + nj) * C_ + c0 + ci] = f2bf(tile[ci * 65 + nj]);
    }
}

// convert qk_w fp32 -> bf16
__global__ __launch_bounds__(256) void k2b_cvt(const float* __restrict__ w,
                                              unsigned short* __restrict__ o, int n)
{
    int i = blockIdx.x * 256 + threadIdx.x;
    if (i < n) o[i] = f2bf(w[i]);
}

// ---------------------------------------------------------------------------
// K3: qk = xs @ qk_w^T via bf16 MFMA 16x16x32, epilogue elu+1, fp32 out.
//     kmean (column means of k-half) fused: shfl-reduce + atomicAdd.
// A [65536][256] bf16, B^T [512][256] bf16, C [65536][512] fp32.
// grid (256, 8), block 256 (4 waves, each 64x64 tile)
// ---------------------------------------------------------------------------
__global__ __launch_bounds__(256) void k3_gemm(
    const short* __restrict__ A, const short* __restrict__ Bw,
    float* __restrict__ qk, float* __restrict__ kmean)
{
    const int t = threadIdx.x, lane = t & 63, wv = t >> 6;
    const int m0 = blockIdx.x * 256 + wv * 64;
    const int n0 = blockIdx.y * 64;
    const int mr = lane & 15, koff = (lane >> 4) * 8;

    f4 acc[4][4];
    #pragma unroll
    for (int a = 0; a < 4; ++a)
        #pragma unroll
        for (int bn = 0; bn < 4; ++bn) { acc[a][bn][0]=0.f; acc[a][bn][1]=0.f; acc[a][bn][2]=0.f; acc[a][bn][3]=0.f; }

    for (int k0 = 0; k0 < 256; k0 += 32) {
        s8 af[4], bf[4];
        #pragma unroll
        for (int mt = 0; mt < 4; ++mt)
            af[mt] = *(const s8*)(A + (size_t)(m0 + mt * 16 + mr) * 256 + k0 + koff);
        #pragma unroll
        for (int nt = 0; nt < 4; ++nt)
            bf[nt] = *(const s8*)(Bw + (size_t)(n0 + nt * 16 + mr) * 256 + k0 + koff);
        #pragma unroll
        for (int mt = 0; mt < 4; ++mt)
            #pragma unroll
            for (int nt = 0; nt < 4; ++nt)
                acc[mt][nt] = __builtin_amdgcn_mfma_f32_16x16x32_bf16(af[mt], bf[nt], acc[mt][nt], 0, 0, 0);
    }

    const int rbase = (lane >> 4) * 4;
    float colacc[4] = {0.f, 0.f, 0.f, 0.f};
    #pragma unroll
    for (int mt = 0; mt < 4; ++mt)
        #pragma unroll
        for (int nt = 0; nt < 4; ++nt)
            #pragma unroll
            for (int r = 0; r < 4; ++r) {
                int m = m0 + mt * 16 + rbase + r;
                int n = n0 + nt * 16 + mr;
                float v = acc[mt][nt][r];
                v = v > 0.f ? v + 1.f : __expf(v);   // elu(v)+1
                qk[(size_t)m * 512 + n] = v;
                colacc[nt] += v;
            }

    if (n0 >= 256) {   // k-half: accumulate column means
        const int bq = blockIdx.x >> 4;
        #pragma unroll
        for (int nt = 0; nt < 4; ++nt) {
            float s = colacc[nt];
            s += __shfl_xor(s, 16);
            s += __shfl_xor(s, 32);
            if (lane < 16)
                atomicAdd(&kmean[bq * 256 + (n0 - 256) + nt * 16 + mr], s * (1.0f / 4096.0f));
        }
    }
}

// ---------------------------------------------------------------------------
// K5: kv[b,h,d,e] = (1/n) sum_n k_rope[n,d] * v[n,e]. split-K over n, atomics.
// grid (16 splits, 4 h, 16 b), block 256
// ---------------------------------------------------------------------------
__global__ __launch_bounds__(256) void k5_kv(
    const float* __restrict__ qk, const unsigned short* __restrict__ xs,
    float* __restrict__ kv)
{
    __shared__ float kl[64 * 68];
    __shared__ float vl[64 * 68];
    const int t = threadIdx.x, lane = t & 63, wv = t >> 6;
    const int split = blockIdx.x, h = blockIdx.y, b = blockIdx.z;
    const int ch = h * 64 + lane;
    const int jj = ch >> 1;
    const float theta = exp2f(-(float)jj * (13.287712379549449f / 128.f)); // 10000^(-jj/128)

    const int d4 = (t & 15) * 4, e4 = (t >> 4) * 4;
    f4 acc4[4];
    #pragma unroll
    for (int i = 0; i < 4; ++i) { acc4[i][0]=0.f; acc4[i][1]=0.f; acc4[i][2]=0.f; acc4[i][3]=0.f; }

    for (int sc = 0; sc < 4; ++sc) {
        const int nbase = split * 256 + sc * 64;
        for (int i = 0; i < 16; ++i) {
            int nl = i * 4 + wv;
            int n = nbase + nl;
            float val = qk[((size_t)b * N_ + n) * 512 + 256 + ch];
            float pv = __shfl_xor(val, 1);
            float ang = (float)(n & 63) * theta;
            float sv, cv; sincosf(ang, &sv, &cv);
            float kr = (lane & 1) ? (sv * pv + cv * val) : (cv * val - sv * pv);
            kl[nl * 68 + lane] = kr;
            vl[nl * 68 + lane] = bf2f(xs[((size_t)b * N_ + n) * 256 + ch]);
        }
        __syncthreads();
        for (int nn = 0; nn < 64; ++nn) {
            f4 kk = *(const f4*)&kl[nn * 68 + d4];
            f4 vv = *(const f4*)&vl[nn * 68 + e4];
            acc4[0] += vv * kk[0];
            acc4[1] += vv * kk[1];
            acc4[2] += vv * kk[2];
            acc4[3] += vv * kk[3];
        }
        __syncthreads();
    }
    const float scale = 1.0f / 4096.0f;
    float* kvp = kv + (size_t)(b * 4 + h) * 4096;
    #pragma unroll
    for (int i = 0; i < 4; ++i)
        #pragma unroll
        for (int j = 0; j < 4; ++j)
            atomicAdd(&kvp[(d4 + i) * 64 + e4 + j], acc4[i][j] * scale);
}

// ---------------------------------------------------------------------------
// K6: attn = (q_rope @ kv) * z, z = 1/(q . kmean + 1e-6); write d_out [b,c,n].
// grid (64 nchunks, 4 h, 16 b), block 256
// ---------------------------------------------------------------------------
__global__ __launch_bounds__(256) void k6_attn(
    const float* __restrict__ qk, const float* __restrict__ kmean,
    const float* __restrict__ kv, float* __restrict__ out)
{
    __shared__ float kvl[64 * 64];
    __shared__ float qT[64 * 68];
    __shared__ float zl[64];
    const int t = threadIdx.x, lane = t & 63, wv = t >> 6;
    const int nt = blockIdx.x, h = blockIdx.y, b = blockIdx.z;
    const int n0 = nt * 64;
    const int ch = h * 64 + lane;
    const int jj = ch >> 1;
    const float theta = exp2f(-(float)jj * (13.287712379549449f / 128.f));
    const float km = kmean[b * 256 + ch];

    for (int i = 0; i < 16; ++i) {
        int flat = i * 256 + t;
        kvl[flat] = kv[(size_t)(b * 4 + h) * 4096 + flat];
    }
    for (int i = 0; i < 16; ++i) {
        int nl = i * 4 + wv;
        int n = n0 + nl;
        float val = qk[((size_t)b * N_ + n) * 512 + ch];
        float pv = __shfl_xor(val, 1);
        float ang = (float)(n & 63) * theta;
        float sv, cv; sincosf(ang, &sv, &cv);
        float qr = (lane & 1) ? (sv * pv + cv * val) : (cv * val - sv * pv);
        qT[lane * 68 + nl] = qr;
        float zd = val * km;
        for (int off = 1; off < 64; off <<= 1) zd += __shfl_xor(zd, off);
        if (lane == 0) zl[nl] = 1.0f / (zd + 1e-6f);
    }
    __syncthreads();

    const int n4 = (t & 15) * 4, e4 = (t >> 4) * 4;
    f4 acc[4];
    #pragma unroll
    for (int j = 0; j < 4; ++j) { acc[j][0]=0.f; acc[j][1]=0.f; acc[j][2]=0.f; acc[j][3]=0.f; }
    for (int dd = 0; dd < 64; ++dd) {
        f4 qq = *(const f4*)&qT[dd * 68 + n4];
        f4 kk = *(const f4*)&kvl[dd * 64 + e4];
        acc[0] += qq * kk[0];
        acc[1] += qq * kk[1];
        acc[2] += qq * kk[2];
        acc[3] += qq * kk[3];
    }
    f4 z4 = *(const f4*)&zl[n4];
    #pragma unroll
    for (int j = 0; j < 4; ++j) acc[j] *= z4;
    #pragma unroll
    for (int j = 0; j < 4; ++j)
        *(f4*)&out[(size_t)(b * 256 + h * 64 + e4 + j) * N_ + n0 + n4] = acc[j];
}

// ---------------------------------------------------------------------------
// K7: LePE 3x3 depthwise conv on fused + bias, RMW-add into d_out.
// grid (256 c, 16 b), block 256
// ---------------------------------------------------------------------------
__global__ __launch_bounds__(256) void k7_lepe(
    const float* __restrict__ fused, const float* __restrict__ lw,
    const float* __restrict__ lb, float* __restrict__ out)
{
    __shared__ float tile[66 * 68];
    const int t = threadIdx.x;
    const int c = blockIdx.x, b = blockIdx.y;
    const float* fc = fused + (size_t)(b * C_ + c) * N_;
    for (int i = 0; i < 18; ++i) {
        int flat = i * 256 + t;
        if (flat < 66 * 68) {
            int r = flat / 68, col = flat % 68;
            int h = r - 1, w = col - 1;
            float v = 0.f;
            if ((unsigned)h < 64u && (unsigned)w < 64u) v = fc[h * 64 + w];
            tile[r * 68 + col] = v;
        }
    }
    __syncthreads();
    float w00 = lw[c*9+0], w01 = lw[c*9+1], w02 = lw[c*9+2];
    float w10 = lw[c*9+3], w11 = lw[c*9+4], w12 = lw[c*9+5];
    float w20 = lw[c*9+6], w21 = lw[c*9+7], w22 = lw[c*9+8];
    float bias = lb[c];
    const int w4 = (t & 15) * 4;
    float* oc = out + (size_t)(b * C_ + c) * N_;
    for (int hh = 0; hh < 4; ++hh) {
        int h = (t >> 4) + hh * 16;
        float r0[6], r1[6], r2[6];
        #pragma unroll
        for (int u = 0; u < 6; ++u) {
            r0[u] = tile[(h + 0) * 68 + w4 + u];
            r1[u] = tile[(h + 1) * 68 + w4 + u];
            r2[u] = tile[(h + 2) * 68 + w4 + u];
        }
        f4 prev = *(const f4*)&oc[h * 64 + w4];
        #pragma unroll
        for (int j = 0; j < 4; ++j) {
            float o = bias;
            o = fmaf(w00, r0[j],   o); o = fmaf(w01, r0[j+1], o); o = fmaf(w02, r0[j+2], o);
            o = fmaf(w10, r1[j],   o); o = fmaf(w11, r1[j+1], o); o = fmaf(w12, r1[j+2], o);
            o = fmaf(w20, r2[j],   o); o = fmaf(w21, r2[j+1], o); o = fmaf(w22, r2[j+2], o);
            prev[j] += o;
        }
        *(f4*)&oc[h * 64 + w4] = prev;
    }
}

// ---------------------------------------------------------------------------
extern "C" void kernel_launch(void* const* d_in, const int* in_sizes, int n_in,
                              void* d_out, int out_size, void* d_ws, size_t ws_size,
                              hipStream_t stream)
{
    const float* x   = (const float*)d_in[0];
    const float* w3  = (const float*)d_in[1];  const float* b3 = (const float*)d_in[2];
    const float* w5  = (const float*)d_in[3];  const float* b5 = (const float*)d_in[4];
    const float* w7  = (const float*)d_in[5];  const float* b7 = (const float*)d_in[6];
    const float* w9  = (const float*)d_in[7];  const float* b9 = (const float*)d_in[8];
    const float* gnw = (const float*)d_in[9];  const float* gnb = (const float*)d_in[10];
    const float* fw  = (const float*)d_in[11];
    const float* qkw = (const float*)d_in[12];
    const float* lw  = (const float*)d_in[13]; const float* lb = (const float*)d_in[14];

    char* ws = (char*)d_ws;
    // layout (bytes):
    //   [0, 128MiB)        y bf16 [4][B][C][N]   -- later ALIASED by qk fp32 [65536][512]
    //   [128MiB, +32MiB)   xs bf16 [B][N][C]
    //   [.. , +64MiB)      fused fp32 [B][C][N]
    //   [.. , +256KiB)     qk_w bf16
    //   [..]               stats (2KB) | kmean (16KB) | kv (4MB)  -- one memset
    unsigned short* y     = (unsigned short*)(ws + 0);
    float*          qk    = (float*)(ws + 0);
    unsigned short* xs    = (unsigned short*)(ws + 134217728ull);
    float*          fused = (float*)(ws + 167772160ull);
    unsigned short* wb    = (unsigned short*)(ws + 234881024ull);
    float*          stats = (float*)(ws + 235143168ull);
    float*          kmean = (float*)(ws + 235145216ull);
    float*          kv    = (float*)(ws + 235161600ull);

    (void)hipMemsetAsync(stats, 0, 2048 + 16384 + 4194304, stream);

    k1_conv_stats<<<dim3(2, 256, 16), 256, 0, stream>>>(x, w3, b3, w5, b5, w7, b7, w9, b9, y, stats);
    k2b_cvt<<<dim3(512), 256, 0, stream>>>(qkw, wb, 131072);
    k2_fuse<<<dim3(64, 4, 16), 256, 0, stream>>>(y, stats, gnw, gnb, fw, xs, fused);
    k3_gemm<<<dim3(256, 8), 256, 0, stream>>>((const short*)xs, (const short*)wb, qk, kmean);
    k5_kv<<<dim3(16, 4, 16), 256, 0, stream>>>(qk, xs, kv);
    k6_attn<<<dim3(64, 4, 16), 256, 0, stream>>>(qk, kmean, kv, (float*)d_out);
    k7_lepe<<<dim3(256, 16), 256, 0, stream>>>(fused, lw, lb, (float*)d_out);
}